// Round 1
// baseline (45.705 us; speedup 1.0000x reference)
//
#include <hip/hip_runtime.h>
#include <hip/hip_bf16.h>

// out[i] = sigmoid(row_avg[i] * w + b), N = 33554432 fp32.
// Pure streaming, memory-bound. float4 vectorized, grid-stride.

__global__ void __launch_bounds__(256) sigmoid_linear_kernel(
    const float* __restrict__ x, const float* __restrict__ wp,
    const float* __restrict__ bp, float* __restrict__ out, int n4) {
    const float w = wp[0];
    const float b = bp[0];
    const float4* __restrict__ x4 = reinterpret_cast<const float4*>(x);
    float4* __restrict__ o4 = reinterpret_cast<float4*>(out);

    int idx = blockIdx.x * blockDim.x + threadIdx.x;
    int stride = gridDim.x * blockDim.x;
    for (int i = idx; i < n4; i += stride) {
        float4 v = x4[i];
        float4 r;
        r.x = 1.0f / (1.0f + __expf(-(v.x * w + b)));
        r.y = 1.0f / (1.0f + __expf(-(v.y * w + b)));
        r.z = 1.0f / (1.0f + __expf(-(v.z * w + b)));
        r.w = 1.0f / (1.0f + __expf(-(v.w * w + b)));
        o4[i] = r;
    }
}

extern "C" void kernel_launch(void* const* d_in, const int* in_sizes, int n_in,
                              void* d_out, int out_size, void* d_ws, size_t ws_size,
                              hipStream_t stream) {
    const float* x = (const float*)d_in[0];   // row_avg, [1, N] fp32
    const float* w = (const float*)d_in[1];   // [1,1]
    const float* b = (const float*)d_in[2];   // [1]
    float* out = (float*)d_out;               // [N] fp32

    const int n = in_sizes[0];                // 33554432
    const int n4 = n >> 2;                    // divisible by 4

    const int block = 256;
    int grid = (n4 + block - 1) / block;
    if (grid > 2048) grid = 2048;

    sigmoid_linear_kernel<<<grid, block, 0, stream>>>(x, w, b, out, n4);
}